// Round 1
// baseline (658.154 us; speedup 1.0000x reference)
//
#include <hip/hip_runtime.h>
#include <cstdint>
#include <cstddef>

typedef short v8s __attribute__((ext_vector_type(8)));
typedef float v4f __attribute__((ext_vector_type(4)));

__device__ inline float bs2f(short s) {
    return __uint_as_float(((unsigned int)(unsigned short)s) << 16);
}
__device__ inline short f2bs(float f) {
    unsigned int u = __float_as_uint(f);
    unsigned int r = (u + 0x7fffu + ((u >> 16) & 1u)) >> 16;  // RNE
    return (short)r;
}

#define MFMA(a, b, c) __builtin_amdgcn_mfma_f32_16x16x32_bf16((a), (b), (c), 0, 0, 0)

// ---------------------------------------------------------------- convert x
__global__ __launch_bounds__(256) void to_bf16(const float* __restrict__ X,
                                               short* __restrict__ Y, int n) {
    int i = (blockIdx.x * 256 + threadIdx.x) * 4;
    if (i < n) {
        float4 v = *(const float4*)(X + i);
        short r[4] = {f2bs(v.x), f2bs(v.y), f2bs(v.z), f2bs(v.w)};
        *(uint2*)(Y + i) = *(const uint2*)r;
    }
}

// ------------------------------------------- transpose W[K,N] -> Wt[N,K] bf16
__global__ __launch_bounds__(256) void transpose_to_bf16(const float* __restrict__ W,
                                                         short* __restrict__ Wt,
                                                         int K, int N) {
    __shared__ float tile[32][33];
    const int tx = threadIdx.x & 31, ty = threadIdx.x >> 5;  // ty 0..7
    const int n0 = blockIdx.x * 32, k0 = blockIdx.y * 32;
#pragma unroll
    for (int i = 0; i < 32; i += 8) tile[ty + i][tx] = W[(size_t)(k0 + ty + i) * N + n0 + tx];
    __syncthreads();
#pragma unroll
    for (int i = 0; i < 32; i += 8)
        Wt[(size_t)(n0 + ty + i) * K + k0 + tx] = f2bs(tile[tx][ty + i]);
}

// ----------------------------------------------------------------- GEMM B^T
// C[M,N] = A[M,K] @ B[K,N],  A bf16 row-major, Bt = B^T bf16 [N,K] row-major.
// 128x128 block tile, 4 waves (2x2), each wave 64x64 = 4x4 MFMA 16x16x32 tiles.
#define GSTRIDE 56  // LDS row stride in shorts: 112B (16B aligned), 2-way banks (free)

__global__ __launch_bounds__(256) void gemm_bt(const short* __restrict__ A,
                                               const short* __restrict__ Bt,
                                               void* __restrict__ C,
                                               int M, int N, int K, int out_f32) {
    __shared__ short As[128 * GSTRIDE];
    __shared__ short Bs[128 * GSTRIDE];
    const int tid = threadIdx.x;
    const int lane = tid & 63, wave = tid >> 6;
    const int l16 = lane & 15, quad = lane >> 4;
    const int wm = (wave >> 1) * 64, wn = (wave & 1) * 64;
    const int m0 = blockIdx.y * 128, n0 = blockIdx.x * 128;

    const v4f VZ = {0.f, 0.f, 0.f, 0.f};
    v4f acc[4][4];
#pragma unroll
    for (int i = 0; i < 4; i++)
#pragma unroll
        for (int j = 0; j < 4; j++) acc[i][j] = VZ;

    const int r0 = tid >> 2;           // staging row (0..63); +64 for second chunk
    const int c0 = (tid & 3) << 3;     // k-offset in shorts (0,8,16,24)

    for (int kk = 0; kk < K; kk += 32) {
        uint4 a0 = *(const uint4*)(A + (size_t)(m0 + r0) * K + kk + c0);
        uint4 a1 = *(const uint4*)(A + (size_t)(m0 + r0 + 64) * K + kk + c0);
        uint4 b0 = *(const uint4*)(Bt + (size_t)(n0 + r0) * K + kk + c0);
        uint4 b1 = *(const uint4*)(Bt + (size_t)(n0 + r0 + 64) * K + kk + c0);
        *(uint4*)(&As[r0 * GSTRIDE + c0]) = a0;
        *(uint4*)(&As[(r0 + 64) * GSTRIDE + c0]) = a1;
        *(uint4*)(&Bs[r0 * GSTRIDE + c0]) = b0;
        *(uint4*)(&Bs[(r0 + 64) * GSTRIDE + c0]) = b1;
        __syncthreads();
        v8s af[4], bfr[4];
#pragma unroll
        for (int t = 0; t < 4; t++)
            af[t] = *(const v8s*)(&As[(wm + t * 16 + l16) * GSTRIDE + quad * 8]);
#pragma unroll
        for (int t = 0; t < 4; t++)
            bfr[t] = *(const v8s*)(&Bs[(wn + t * 16 + l16) * GSTRIDE + quad * 8]);
#pragma unroll
        for (int i = 0; i < 4; i++)
#pragma unroll
            for (int j = 0; j < 4; j++) acc[i][j] = MFMA(af[i], bfr[j], acc[i][j]);
        __syncthreads();
    }

#pragma unroll
    for (int i = 0; i < 4; i++) {
#pragma unroll
        for (int r = 0; r < 4; r++) {
            const int row = m0 + wm + i * 16 + quad * 4 + r;
#pragma unroll
            for (int j = 0; j < 4; j++) {
                const int col = n0 + wn + j * 16 + l16;
                float v = acc[i][j][r];
                if (out_f32) ((float*)C)[(size_t)row * N + col] = v;
                else ((short*)C)[(size_t)row * N + col] = f2bs(v);
            }
        }
    }
}

// ------------------------------------------------------------- RMSNorm (q)
// rows of 128 (one per (token,head)); one wave per row; scale folds 1/sqrt(D).
__global__ __launch_bounds__(256) void rmsnorm_q(const short* __restrict__ X,
                                                 const float* __restrict__ g,
                                                 short* __restrict__ Y, float scale) {
    const int row = blockIdx.x * 4 + (threadIdx.x >> 6);
    const int lane = threadIdx.x & 63;
    const short* p = X + (size_t)row * 128;
    float a = bs2f(p[lane]);
    float c = bs2f(p[lane + 64]);
    float ss = a * a + c * c;
#pragma unroll
    for (int off = 1; off < 64; off <<= 1) ss += __shfl_xor(ss, off);
    float rs = rsqrtf(ss * (1.f / 128.f) + 1e-6f) * scale;
    Y[(size_t)row * 128 + lane] = f2bs(a * rs * g[lane]);
    Y[(size_t)row * 128 + lane + 64] = f2bs(c * rs * g[lane + 64]);
}

// ------------------------------------------------------------- RMSNorm (k)
// concat(kr[m,h,0:64], kn[m,h,0:64]) -> normalized k[m,h,0:128]
__global__ __launch_bounds__(256) void rmsnorm_k(const short* __restrict__ KR,
                                                 const short* __restrict__ KN,
                                                 const float* __restrict__ g,
                                                 short* __restrict__ Y) {
    const int rh = blockIdx.x * 4 + (threadIdx.x >> 6);  // m*16+h
    const int m = rh >> 4, h = rh & 15;
    const int lane = threadIdx.x & 63;
    float a = bs2f(KR[(size_t)m * 1024 + h * 64 + lane]);
    float c = bs2f(KN[(size_t)m * 1024 + h * 64 + lane]);
    float ss = a * a + c * c;
#pragma unroll
    for (int off = 1; off < 64; off <<= 1) ss += __shfl_xor(ss, off);
    float rs = rsqrtf(ss * (1.f / 128.f) + 1e-6f);
    Y[(size_t)rh * 128 + lane] = f2bs(a * rs * g[lane]);
    Y[(size_t)rh * 128 + 64 + lane] = f2bs(c * rs * g[lane + 64]);
}

// ------------------------------------------------------ flash attention (causal)
// Q,K,V,O: bf16 [B,S,H,D] = [b*S+s][h*128+d].  64 q-rows/block (16/wave),
// 64-key tiles.  Scale pre-folded into Q.
#define KSTR 136  // Ks [key][d] row stride (shorts): 272B, 16B-aligned, 2-way banks
#define VSTR 72   // Vs [d][key] row stride: 144B
#define PSTR 72   // Ps [qrow][key] row stride

__global__ __launch_bounds__(256) void flash_attn(const short* __restrict__ Q,
                                                  const short* __restrict__ Kb,
                                                  const short* __restrict__ Vb,
                                                  short* __restrict__ O, int S) {
    __shared__ short Ks[64 * KSTR];
    __shared__ short Vs[128 * VSTR];
    __shared__ short Ps[4][16 * PSTR];

    const int tid = threadIdx.x;
    const int lane = tid & 63, w = tid >> 6;
    const int l16 = lane & 15, quad = lane >> 4;
    const int bh = blockIdx.y;
    const int b = bh >> 4, h = bh & 15;
    const int q0 = blockIdx.x * 64;

    // Q fragments: A-layout m=l16 (query within wave tile), k = quad*8+j (d)
    const size_t qbase = ((size_t)(b * S + q0 + w * 16 + l16) * 16 + h) * 128;
    v8s aq[4];
#pragma unroll
    for (int kc = 0; kc < 4; kc++) aq[kc] = *(const v8s*)(Q + qbase + kc * 32 + quad * 8);

    const v4f VZ = {0.f, 0.f, 0.f, 0.f};
    v4f accO[8];
#pragma unroll
    for (int d = 0; d < 8; d++) accO[d] = VZ;
    float mr[4], lr[4];
#pragma unroll
    for (int r = 0; r < 4; r++) { mr[r] = -1e30f; lr[r] = 0.f; }

    const int nkt = blockIdx.x + 1;
    const int skey = tid >> 2;         // staging key row (0..63)
    const int sc0 = (tid & 3) * 4;     // first 8-elem chunk of 16 within the row

    for (int kt = 0; kt < nkt; ++kt) {
        const int k0 = kt * 64;
        __syncthreads();  // protect LDS reuse vs previous iteration's reads
        {
            const size_t srcbase = ((size_t)(b * S + k0 + skey) * 16 + h) * 128;
#pragma unroll
            for (int i = 0; i < 4; i++) {
                const int c8 = sc0 + i;
                uint4 kv = *(const uint4*)(Kb + srcbase + c8 * 8);
                *(uint4*)(&Ks[skey * KSTR + c8 * 8]) = kv;
                uint4 vv = *(const uint4*)(Vb + srcbase + c8 * 8);
                const short* vp = (const short*)&vv;
#pragma unroll
                for (int j = 0; j < 8; j++) Vs[(c8 * 8 + j) * VSTR + skey] = vp[j];
            }
        }
        __syncthreads();

        // S-tile = Q K^T  (16 queries x 64 keys per wave)
        v4f sc[4];
#pragma unroll
        for (int nt = 0; nt < 4; nt++) {
            v4f s = VZ;
#pragma unroll
            for (int kc = 0; kc < 4; kc++) {
                v8s bk = *(const v8s*)(&Ks[(nt * 16 + l16) * KSTR + kc * 32 + quad * 8]);
                s = MFMA(aq[kc], bk, s);
            }
            sc[nt] = s;
        }

        // mask + online softmax (rows quad*4+r, distributed over 16 lanes/quad)
        const int qrow = q0 + w * 16 + quad * 4;
        const int kcol = k0 + l16;
#pragma unroll
        for (int r = 0; r < 4; r++) {
            float s0[4];
#pragma unroll
            for (int nt = 0; nt < 4; nt++) {
                float v = sc[nt][r];
                if (kcol + nt * 16 > qrow + r) v = -1e30f;
                s0[nt] = v;
            }
            float tmax = fmaxf(fmaxf(s0[0], s0[1]), fmaxf(s0[2], s0[3]));
#pragma unroll
            for (int off = 1; off < 16; off <<= 1) tmax = fmaxf(tmax, __shfl_xor(tmax, off));
            float mnew = fmaxf(mr[r], tmax);
            float alpha = __expf(mr[r] - mnew);
            float rsum = 0.f;
#pragma unroll
            for (int nt = 0; nt < 4; nt++) {
                float p = __expf(s0[nt] - mnew);
                rsum += p;
                Ps[w][(quad * 4 + r) * PSTR + nt * 16 + l16] = f2bs(p);
            }
#pragma unroll
            for (int off = 1; off < 16; off <<= 1) rsum += __shfl_xor(rsum, off);
            lr[r] = lr[r] * alpha + rsum;
            mr[r] = mnew;
#pragma unroll
            for (int d = 0; d < 8; d++) accO[d][r] *= alpha;
        }
        __syncthreads();  // P visible for A-layout re-read

        // O += P V   (P: A-layout from Ps, V: B-layout from transposed Vs)
#pragma unroll
        for (int dt = 0; dt < 8; dt++) {
#pragma unroll
            for (int kc2 = 0; kc2 < 2; kc2++) {
                v8s ap = *(const v8s*)(&Ps[w][l16 * PSTR + kc2 * 32 + quad * 8]);
                v8s bv = *(const v8s*)(&Vs[(dt * 16 + l16) * VSTR + kc2 * 32 + quad * 8]);
                accO[dt] = MFMA(ap, bv, accO[dt]);
            }
        }
    }

#pragma unroll
    for (int r = 0; r < 4; r++) {
        const int qg = q0 + w * 16 + quad * 4 + r;
        const float inv = 1.f / lr[r];
        const size_t obase = ((size_t)(b * S + qg) * 16 + h) * 128;
#pragma unroll
        for (int dt = 0; dt < 8; dt++) O[obase + dt * 16 + l16] = f2bs(accO[dt][r] * inv);
    }
}

// ---------------------------------------------------------------------------
extern "C" void kernel_launch(void* const* d_in, const int* in_sizes, int n_in,
                              void* d_out, int out_size, void* d_ws, size_t ws_size,
                              hipStream_t stream) {
    (void)in_sizes; (void)n_in; (void)out_size; (void)ws_size;
    const float* x   = (const float*)d_in[0];
    const float* Wq  = (const float*)d_in[1];
    const float* Wkv = (const float*)d_in[2];
    const float* Wkr = (const float*)d_in[3];
    const float* Wkn = (const float*)d_in[4];
    const float* Wv  = (const float*)d_in[5];
    const float* Wo  = (const float*)d_in[6];
    const float* gq  = (const float*)d_in[7];
    const float* gk  = (const float*)d_in[8];

    const int B = 2, S = 2048, HID = 2048, H = 16;
    const int M = B * S;  // 4096

    char* ws = (char*)d_ws;
    size_t off = 0;
    auto alloc = [&](size_t bytes) {
        char* p = ws + off;
        off += (bytes + 255) & ~(size_t)255;
        return p;
    };
    short* xb   = (short*)alloc((size_t)M * HID * 2);
    short* Wqt  = (short*)alloc((size_t)2048 * 2048 * 2);
    short* Wkvt = (short*)alloc((size_t)512 * 2048 * 2);
    short* Wkrt = (short*)alloc((size_t)1024 * 512 * 2);
    short* Wknt = (short*)alloc((size_t)1024 * 512 * 2);
    short* Wvt  = (short*)alloc((size_t)2048 * 512 * 2);
    short* Wot  = (short*)alloc((size_t)2048 * 2048 * 2);
    short* qraw = (short*)alloc((size_t)M * 2048 * 2);
    short* qb   = (short*)alloc((size_t)M * 2048 * 2);
    short* lat  = (short*)alloc((size_t)M * 512 * 2);
    short* krr  = (short*)alloc((size_t)M * 1024 * 2);
    short* knr  = (short*)alloc((size_t)M * 1024 * 2);
    short* kb   = (short*)alloc((size_t)M * 2048 * 2);
    short* vb   = (short*)alloc((size_t)M * 2048 * 2);
    short* ob   = qraw;  // qraw dead after rmsnorm_q; reuse for attention output

    to_bf16<<<(M * HID) / 1024, 256, 0, stream>>>(x, xb, M * HID);
    transpose_to_bf16<<<dim3(2048 / 32, 2048 / 32), 256, 0, stream>>>(Wq, Wqt, 2048, 2048);
    transpose_to_bf16<<<dim3(512 / 32, 2048 / 32), 256, 0, stream>>>(Wkv, Wkvt, 2048, 512);
    transpose_to_bf16<<<dim3(1024 / 32, 512 / 32), 256, 0, stream>>>(Wkr, Wkrt, 512, 1024);
    transpose_to_bf16<<<dim3(1024 / 32, 512 / 32), 256, 0, stream>>>(Wkn, Wknt, 512, 1024);
    transpose_to_bf16<<<dim3(2048 / 32, 512 / 32), 256, 0, stream>>>(Wv, Wvt, 512, 2048);
    transpose_to_bf16<<<dim3(2048 / 32, 2048 / 32), 256, 0, stream>>>(Wo, Wot, 2048, 2048);

    // q = rmsnorm(x @ Wq) * gq * (1/sqrt(128))
    gemm_bt<<<dim3(2048 / 128, M / 128), 256, 0, stream>>>(xb, Wqt, qraw, M, 2048, 2048, 0);
    rmsnorm_q<<<(M * H) / 4, 256, 0, stream>>>(qraw, gq, qb, 0.08838834764831845f);

    // lat = x @ Wkv
    gemm_bt<<<dim3(512 / 128, M / 128), 256, 0, stream>>>(xb, Wkvt, lat, M, 512, 2048, 0);
    // kr / kn, then k = rmsnorm(concat)
    gemm_bt<<<dim3(1024 / 128, M / 128), 256, 0, stream>>>(lat, Wkrt, krr, M, 1024, 512, 0);
    gemm_bt<<<dim3(1024 / 128, M / 128), 256, 0, stream>>>(lat, Wknt, knr, M, 1024, 512, 0);
    rmsnorm_k<<<(M * H) / 4, 256, 0, stream>>>(krr, knr, gk, kb);
    // v = lat @ Wv
    gemm_bt<<<dim3(2048 / 128, M / 128), 256, 0, stream>>>(lat, Wvt, vb, M, 2048, 512, 0);

    // causal SDPA
    flash_attn<<<dim3(S / 64, B * H), 256, 0, stream>>>(qb, kb, vb, ob, S);

    // out = o @ Wo  (fp32 output)
    gemm_bt<<<dim3(2048 / 128, M / 128), 256, 0, stream>>>(ob, Wot, d_out, M, 2048, 2048, 1);
}